// Round 6
// baseline (80.032 us; speedup 1.0000x reference)
//
#include <hip/hip_runtime.h>
#include <hip/hip_bf16.h>

#define NQ 10000
#define BATCH 64
#define SEQL 200
#define DKD 128
#define SLOTS 64
#define NTOK (BATCH*SEQL)

typedef __attribute__((ext_vector_type(8))) short bh8;
typedef __attribute__((ext_vector_type(4))) float f32x4;
typedef unsigned short u16;
typedef unsigned int u32;

__device__ __forceinline__ float sigmoidf_(float x){ return 1.0f/(1.0f + __expf(-x)); }
__device__ __forceinline__ float tanhf_(float x){
  float ax = fminf(fabsf(x), 30.0f);
  float t = __expf(-2.0f*ax);
  float r = (1.0f-t)/(1.0f+t);
  return copysignf(r, x);
}
// fp32 -> bf16 round-to-nearest-even (bit pattern)
__device__ __forceinline__ u16 f2b(float x){
  u32 u = __builtin_bit_cast(u32, x);
  u32 r = (u + 0x7FFFu + ((u >> 16) & 1u)) >> 16;
  return (u16)r;
}
// convert 8 consecutive fp32 at s -> bh8
__device__ __forceinline__ bh8 cvt8(const float* s){
  float4 v0 = *(const float4*)s, v1 = *(const float4*)(s + 4);
  bh8 h;
  h[0]=(short)f2b(v0.x); h[1]=(short)f2b(v0.y); h[2]=(short)f2b(v0.z); h[3]=(short)f2b(v0.w);
  h[4]=(short)f2b(v1.x); h[5]=(short)f2b(v1.y); h[6]=(short)f2b(v1.z); h[7]=(short)f2b(v1.w);
  return h;
}
// physical byte offset of logical (row, col16) in a row-major LDS tile,
// G4 XOR swizzle (16-lane stride-row MFMA fragment reads otherwise 16-way conflict)
__device__ __forceinline__ int swz(int row, int col16, int rowBytes){
  return row*rowBytes + ((col16 ^ (row & 7)) << 4);
}

// ---------------- WEA: blocks 0..399 = W (softmax(k Mk^T)); 400..799 = E/A ----------------
// 512 thr = 8 waves; 32 tok/block; MFMA 16x16x32 bf16.
// ALL outputs transposed: wT[b][s][t], eT/aT[b][d][t] (t-contiguous float4 per lane).
__global__ __launch_bounds__(512) void wea_kernel(
    const int* __restrict__ qseq, const int* __restrict__ cseq,
    const float* __restrict__ q_emb, const float* __restrict__ v_emb,
    const float* __restrict__ Mk, const float* __restrict__ eW,
    const float* __restrict__ aW,
    const float* __restrict__ eb, const float* __restrict__ ab,
    float* __restrict__ wT, float* __restrict__ eT, float* __restrict__ aT)
{
  __shared__ __align__(16) char smem[73728];
  char* As = smem;                       // A tile [32 rows][256B]
  char* Bs = smem + 8192;                // W: Mk [64][256B]; EA: [256][256B]
  float* Ls = (float*)(smem + 24576);    // W logits [32][68] f32

  const int tid = threadIdx.x;
  const int l = tid & 63, wv = tid >> 6;
  const bool isW = (blockIdx.x < 400);
  const int tok0 = (isW ? blockIdx.x : blockIdx.x - 400) * 32;

  { // stage A: gather 32 embedding rows, cvt fp32->bf16, swizzled write (1 chunk/thread)
    int row = tid >> 4, c16 = tid & 15;
    const float* src;
    if (isW){ int q = qseq[tok0+row]; src = q_emb + (size_t)q*DKD + c16*8; }
    else    { int x = qseq[tok0+row] + NQ*cseq[tok0+row]; src = v_emb + (size_t)x*DKD + c16*8; }
    *(bh8*)(As + swz(row, c16, 256)) = cvt8(src);
  }
  if (isW){ // stage B = Mk (64 rows x 16 chunks), fp32 -> bf16
    #pragma unroll
    for (int m = 0; m < 2; ++m){
      int idx = tid + 512*m; int row = idx >> 4, c16 = idx & 15;
      *(bh8*)(Bs + swz(row, c16, 256)) = cvt8(Mk + (size_t)row*DKD + c16*8);
    }
  } else {  // stage B = [eW; aW] (256 rows x 16 chunks), fp32 -> bf16
    #pragma unroll
    for (int m = 0; m < 8; ++m){
      int idx = tid + 512*m; int row = idx >> 4, c16 = idx & 15;
      const float* src = (row < 128) ? (eW + (size_t)row*DKD) : (aW + (size_t)(row-128)*DKD);
      *(bh8*)(Bs + swz(row, c16, 256)) = cvt8(src + c16*8);
    }
  }
  __syncthreads();

  if (isW){
    const int m = wv & 1, n = wv >> 1;        // 8 waves -> 8 output tiles
    f32x4 acc = {0.f,0.f,0.f,0.f};
    #pragma unroll
    for (int kc = 0; kc < 4; ++kc){
      bh8 af = *(const bh8*)(As + swz(m*16 + (l&15), kc*4 + (l>>4), 256));
      bh8 bf = *(const bh8*)(Bs + swz(n*16 + (l&15), kc*4 + (l>>4), 256));
      acc = __builtin_amdgcn_mfma_f32_16x16x32_bf16(af, bf, acc, 0, 0, 0);
    }
    #pragma unroll
    for (int r = 0; r < 4; ++r){
      int tok = m*16 + (l>>4)*4 + r, out = n*16 + (l&15);
      Ls[tok*68 + out] = acc[r];
    }
    __syncthreads();
    // softmax: wave wv owns tokens 4wv..4wv+3 (consecutive t, same b since 4|200);
    // lane = slot. Collect the 4 results and store one float4 to wT[b][s][t].
    f32x4 ps;
    #pragma unroll
    for (int i = 0; i < 4; ++i){
      int tok = wv*4 + i;
      float x = Ls[tok*68 + l];
      float mx = x;
      #pragma unroll
      for (int off = 32; off >= 1; off >>= 1) mx = fmaxf(mx, __shfl_xor(mx, off));
      float p = __expf(x - mx);
      float s = p;
      #pragma unroll
      for (int off = 32; off >= 1; off >>= 1) s += __shfl_xor(s, off);
      ps[i] = p / s;
    }
    int tg = tok0 + wv*4;
    int bb = tg / SEQL, tl = tg - bb*SEQL;
    *(f32x4*)(wT + ((size_t)bb*SLOTS + l)*SEQL + tl) = ps;
  } else {
    const int m = wv & 1, nq = (wv >> 1) * 4; // 4 n-tiles per wave
    f32x4 acc[4] = {{0.f,0.f,0.f,0.f},{0.f,0.f,0.f,0.f},{0.f,0.f,0.f,0.f},{0.f,0.f,0.f,0.f}};
    #pragma unroll
    for (int kc = 0; kc < 4; ++kc){
      bh8 af = *(const bh8*)(As + swz(m*16 + (l&15), kc*4 + (l>>4), 256));
      #pragma unroll
      for (int j = 0; j < 4; ++j){
        bh8 bf = *(const bh8*)(Bs + swz((nq+j)*16 + (l&15), kc*4 + (l>>4), 256));
        acc[j] = __builtin_amdgcn_mfma_f32_16x16x32_bf16(af, bf, acc[j], 0, 0, 0);
      }
    }
    // transposed store: 4 acc values = 4 consecutive tokens at fixed d -> one float4
    #pragma unroll
    for (int j = 0; j < 4; ++j){
      int out = (nq+j)*16 + (l&15);
      bool is_e = (out < 128);
      int dd = out & 127;
      float bias = is_e ? eb[dd] : ab[dd];
      f32x4 sv;
      #pragma unroll
      for (int r = 0; r < 4; ++r){
        float xv = acc[j][r] + bias;
        sv[r] = is_e ? sigmoidf_(xv) : tanhf_(xv);
      }
      int tg = tok0 + m*16 + (l>>4)*4;       // first of 4 consecutive tokens
      int bb = tg / SEQL, tl = tg - bb*SEQL;
      float* dst = (is_e ? eT : aT) + ((size_t)bb*DKD + dd)*SEQL + tl;
      *(f32x4*)dst = sv;
    }
  }
}

// ---------------- Scan: ZERO LDS / ZERO barriers. All operands t-contiguous per lane. ----
// Block = (b, 16 d); 512 blocks x 256 thr; wave = 4 independent chains.
// 3-set register rotation -> prefetch distance 2 chunks; loads never drained by barriers.
__device__ __forceinline__ float dpp_row_sum16(float x){
  float t;
  t = __builtin_bit_cast(float, __builtin_amdgcn_update_dpp(0, __builtin_bit_cast(int,x), 0x111, 0xf, 0xf, true)); x += t; // row_shr:1
  t = __builtin_bit_cast(float, __builtin_amdgcn_update_dpp(0, __builtin_bit_cast(int,x), 0x112, 0xf, 0xf, true)); x += t; // row_shr:2
  t = __builtin_bit_cast(float, __builtin_amdgcn_update_dpp(0, __builtin_bit_cast(int,x), 0x114, 0xf, 0xf, true)); x += t; // row_shr:4
  t = __builtin_bit_cast(float, __builtin_amdgcn_update_dpp(0, __builtin_bit_cast(int,x), 0x118, 0xf, 0xf, true)); x += t; // row_shr:8
  return x;  // lane 15 (mod 16) holds the 16-lane sum
}

#define SCH 4     // t per chunk
#define SNCH 50   // 50*4 = 200 exactly

__global__ __launch_bounds__(256) void scan_kernel(
    const float* __restrict__ Mv0,
    const float* __restrict__ wT,   // [b][64 s][200 t]
    const float* __restrict__ eT,   // [b][128 d][200 t]
    const float* __restrict__ aT,
    u16* __restrict__ r16)          // [b][200 t][128 d]
{
  const int tid = threadIdx.x;
  const int b  = blockIdx.x >> 3;
  const int d0 = (blockIdx.x & 7) << 4;
  const int c  = tid >> 4;          // chain: d = d0 + c (4 chains per wave)
  const int g  = tid & 15;          // slot quad: slots 4g..4g+3
  const int d  = d0 + c;
  const bool wl = (g == 15);

  float mv0 = Mv0[(4*g+0)*DKD + d];
  float mv1 = Mv0[(4*g+1)*DKD + d];
  float mv2 = Mv0[(4*g+2)*DKD + d];
  float mv3 = Mv0[(4*g+3)*DKD + d];

  const float* wbase = wT + ((size_t)b*SLOTS + 4*g)*SEQL;
  const float* ebase = eT + ((size_t)b*DKD + d)*SEQL;
  const float* abase = aT + ((size_t)b*DKD + d)*SEQL;
  u16* rp = r16 + (size_t)b*SEQL*DKD + d;

  f32x4 Aw0,Aw1,Aw2,Aw3,Ae,Aa;
  f32x4 Bw0,Bw1,Bw2,Bw3,Be,Ba;
  f32x4 Cw0,Cw1,Cw2,Cw3,Ce,Ca;

  #define LOADS(S, CK) { const int t0_ = (CK)*SCH;                        \
    S##w0 = *(const f32x4*)(wbase + 0*SEQL + t0_);                        \
    S##w1 = *(const f32x4*)(wbase + 1*SEQL + t0_);                        \
    S##w2 = *(const f32x4*)(wbase + 2*SEQL + t0_);                        \
    S##w3 = *(const f32x4*)(wbase + 3*SEQL + t0_);                        \
    S##e  = *(const f32x4*)(ebase + t0_);                                 \
    S##a  = *(const f32x4*)(abase + t0_); }

  #define CHUNK(S, CK) {                                                  \
    float rr[SCH];                                                        \
    _Pragma("unroll")                                                     \
    for (int v = 0; v < SCH; ++v){                                        \
      const float w0 = S##w0[v], w1 = S##w1[v], w2 = S##w2[v], w3 = S##w3[v]; \
      float r = w0*mv0; r = fmaf(w1, mv1, r);                             \
      r = fmaf(w2, mv2, r); r = fmaf(w3, mv3, r);                         \
      rr[v] = dpp_row_sum16(r);                                           \
      const float ev = S##e[v], av = S##a[v];                             \
      mv0 = fmaf(w0, fmaf(-mv0, ev, av), mv0);                            \
      mv1 = fmaf(w1, fmaf(-mv1, ev, av), mv1);                            \
      mv2 = fmaf(w2, fmaf(-mv2, ev, av), mv2);                            \
      mv3 = fmaf(w3, fmaf(-mv3, ev, av), mv3);                            \
    }                                                                     \
    if (wl){                                                              \
      _Pragma("unroll")                                                   \
      for (int v = 0; v < SCH; ++v)                                       \
        rp[(size_t)((CK)*SCH + v)*DKD] = f2b(rr[v]);                      \
    } }

  LOADS(A, 0)
  LOADS(B, 1)
  #pragma unroll 1
  for (int m = 0; m < 16; ++m){
    const int ck = 3*m;
    LOADS(C, ck+2)  CHUNK(A, ck)
    LOADS(A, ck+3)  CHUNK(B, ck+1)
    LOADS(B, ck+4)  CHUNK(C, ck+2)
  }
  CHUNK(A, 48)
  CHUNK(B, 49)
  #undef LOADS
  #undef CHUNK
}

// ---------------- P3: f = tanh([read|k] fW^T + fb); out = sigmoid(f pW + pb) ----------------
// 512 thr = 8 waves; 32 tok/block; A = [r16 | k] bf16 (K=256), B = fW cvt'd. LDS 80 KiB.
__global__ __launch_bounds__(512) void p3_kernel(
    const int* __restrict__ qseq, const float* __restrict__ q_emb,
    const u16* __restrict__ r16, const float* __restrict__ fW,
    const float* __restrict__ fb, const float* __restrict__ pW,
    const float* __restrict__ pb, float* __restrict__ out)
{
  __shared__ __align__(16) char smem[81920];
  char* As = smem;            // [32 rows][512B]
  char* Bs = smem + 16384;    // [128 rows][512B]

  const int tid = threadIdx.x;
  const int l = tid & 63, wv = tid >> 6;
  const int tok0 = blockIdx.x * 32;

  #pragma unroll
  for (int m = 0; m < 2; ++m){   // stage A: 1024 chunks (rows 512B = 32 chunks)
    int idx = tid + 512*m; int row = idx >> 5, c16 = idx & 31;
    bh8 v;
    if (c16 < 16){
      v = *(const bh8*)(r16 + (size_t)(tok0+row)*DKD + c16*8);
    } else {
      int q = qseq[tok0+row];
      v = cvt8(q_emb + (size_t)q*DKD + (c16-16)*8);
    }
    *(bh8*)(As + swz(row, c16, 512)) = v;
  }
  #pragma unroll
  for (int m = 0; m < 8; ++m){   // stage B: 4096 chunks, fp32 fW -> bf16
    int idx = tid + 512*m; int row = idx >> 5, c16 = idx & 31;
    *(bh8*)(Bs + swz(row, c16, 512)) = cvt8(fW + (size_t)row*256 + c16*8);
  }
  __syncthreads();

  const int m = wv & 1, np = (wv >> 1) * 2;   // 2 n-tiles per wave
  f32x4 acc[2] = {{0.f,0.f,0.f,0.f},{0.f,0.f,0.f,0.f}};
  #pragma unroll
  for (int kc = 0; kc < 8; ++kc){
    bh8 af = *(const bh8*)(As + swz(m*16 + (l&15), kc*4 + (l>>4), 512));
    #pragma unroll
    for (int j = 0; j < 2; ++j){
      bh8 bf = *(const bh8*)(Bs + swz((np+j)*16 + (l&15), kc*4 + (l>>4), 512));
      acc[j] = __builtin_amdgcn_mfma_f32_16x16x32_bf16(af, bf, acc[j], 0, 0, 0);
    }
  }
  // per-lane partial p over this wave's 32 out-columns
  float pp[4] = {0.f,0.f,0.f,0.f};
  #pragma unroll
  for (int j = 0; j < 2; ++j){
    int o = (np+j)*16 + (l&15);
    float bias = fb[o], pw = pW[o];
    #pragma unroll
    for (int r = 0; r < 4; ++r){
      float f = tanhf_(acc[j][r] + bias);
      pp[r] = fmaf(f, pw, pp[r]);
    }
  }
  #pragma unroll
  for (int r = 0; r < 4; ++r){   // reduce across the 16 out-lanes
    pp[r] += __shfl_xor(pp[r], 1);
    pp[r] += __shfl_xor(pp[r], 2);
    pp[r] += __shfl_xor(pp[r], 4);
    pp[r] += __shfl_xor(pp[r], 8);
  }
  __syncthreads();
  float* pbuf = (float*)smem;    // overlay on As (done with it): [8 waves][32 tok]
  if ((l & 15) == 0){
    #pragma unroll
    for (int r = 0; r < 4; ++r){
      int tok = m*16 + (l>>4)*4 + r;
      pbuf[wv*32 + tok] = pp[r];
    }
  }
  __syncthreads();
  if (tid < 32){
    int mm = tid >> 4;   // token's m-half -> waves with wv&1 == mm
    float s = pbuf[(mm+0)*32 + tid] + pbuf[(mm+2)*32 + tid]
            + pbuf[(mm+4)*32 + tid] + pbuf[(mm+6)*32 + tid];
    out[tok0 + tid] = sigmoidf_(s + pb[0]);
  }
}

extern "C" void kernel_launch(void* const* d_in, const int* in_sizes, int n_in,
                              void* d_out, int out_size, void* d_ws, size_t ws_size,
                              hipStream_t stream) {
  const int*   qseq  = (const int*)d_in[0];
  const int*   cseq  = (const int*)d_in[1];
  const float* q_emb = (const float*)d_in[2];
  const float* v_emb = (const float*)d_in[3];
  const float* Mk    = (const float*)d_in[4];
  const float* Mv0   = (const float*)d_in[5];
  const float* eW    = (const float*)d_in[6];
  const float* eb    = (const float*)d_in[7];
  const float* aW    = (const float*)d_in[8];
  const float* ab    = (const float*)d_in[9];
  const float* fW    = (const float*)d_in[10];
  const float* fb    = (const float*)d_in[11];
  const float* pW    = (const float*)d_in[12];
  const float* pb    = (const float*)d_in[13];

  char* ws = (char*)d_ws;
  float* wT    = (float*)ws;                                   // 64*64*200*4  = 3,276,800
  float* eT    = (float*)(ws + 3276800);                       // 64*128*200*4 = 6,553,600
  float* aT    = (float*)(ws + 9830400);                       // 6,553,600
  u16*   r16   = (u16*)  (ws + 16384000);                      // 12800*128*2  = 3,276,800 (end ~19.7 MB)
  float* outp  = (float*)d_out;

  hipLaunchKernelGGL(wea_kernel, dim3(800), dim3(512), 0, stream,
                     qseq, cseq, q_emb, v_emb, Mk, eW, aW, eb, ab,
                     wT, eT, aT);
  hipLaunchKernelGGL(scan_kernel, dim3(512), dim3(256), 0, stream,
                     Mv0, wT, eT, aT, r16);
  hipLaunchKernelGGL(p3_kernel, dim3(NTOK/32), dim3(512), 0, stream,
                     qseq, q_emb, r16, fW, fb, pW, pb, outp);
}

// Round 7
// 53.324 us; speedup vs baseline: 1.5009x; 1.5009x over previous
//
#include <hip/hip_runtime.h>
#include <hip/hip_bf16.h>

#define NQ 10000
#define BATCH 64
#define SEQL 200
#define DKD 128
#define SLOTS 64
#define NTOK (BATCH*SEQL)

typedef __attribute__((ext_vector_type(8))) short bh8;
typedef __attribute__((ext_vector_type(4))) float f32x4;
typedef unsigned short u16;
typedef unsigned int u32;

__device__ __forceinline__ float sigmoidf_(float x){ return 1.0f/(1.0f + __expf(-x)); }
__device__ __forceinline__ float tanhf_(float x){
  float ax = fminf(fabsf(x), 30.0f);
  float t = __expf(-2.0f*ax);
  float r = (1.0f-t)/(1.0f+t);
  return copysignf(r, x);
}
// fp32 -> bf16 round-to-nearest-even (bit pattern)
__device__ __forceinline__ u16 f2b(float x){
  u32 u = __builtin_bit_cast(u32, x);
  u32 r = (u + 0x7FFFu + ((u >> 16) & 1u)) >> 16;
  return (u16)r;
}
// convert 8 consecutive fp32 at s -> bh8
__device__ __forceinline__ bh8 cvt8(const float* s){
  float4 v0 = *(const float4*)s, v1 = *(const float4*)(s + 4);
  bh8 h;
  h[0]=(short)f2b(v0.x); h[1]=(short)f2b(v0.y); h[2]=(short)f2b(v0.z); h[3]=(short)f2b(v0.w);
  h[4]=(short)f2b(v1.x); h[5]=(short)f2b(v1.y); h[6]=(short)f2b(v1.z); h[7]=(short)f2b(v1.w);
  return h;
}
// physical byte offset of logical (row, col16) in a row-major LDS tile,
// G4 XOR swizzle (16-lane stride-row MFMA fragment reads otherwise 16-way conflict)
__device__ __forceinline__ int swz(int row, int col16, int rowBytes){
  return row*rowBytes + ((col16 ^ (row & 7)) << 4);
}

// ---------------- WEA: blocks 0..399 = W (softmax(k Mk^T)); 400..799 = E/A ----------------
// 512 thr = 8 waves; 32 tok/block; MFMA 16x16x32 bf16.
// w written row-major [b][t][s]; e/a written TRANSPOSED [b][d][t].
__global__ __launch_bounds__(512) void wea_kernel(
    const int* __restrict__ qseq, const int* __restrict__ cseq,
    const float* __restrict__ q_emb, const float* __restrict__ v_emb,
    const float* __restrict__ Mk, const float* __restrict__ eW,
    const float* __restrict__ aW,
    const float* __restrict__ eb, const float* __restrict__ ab,
    float* __restrict__ w_out, float* __restrict__ eT, float* __restrict__ aT)
{
  __shared__ __align__(16) char smem[73728];
  char* As = smem;                       // A tile [32 rows][256B]
  char* Bs = smem + 8192;                // W: Mk [64][256B]; EA: [256][256B]
  float* Ls = (float*)(smem + 24576);    // W logits [32][68] f32

  const int tid = threadIdx.x;
  const int l = tid & 63, wv = tid >> 6;
  const bool isW = (blockIdx.x < 400);
  const int tok0 = (isW ? blockIdx.x : blockIdx.x - 400) * 32;

  { // stage A: gather 32 embedding rows, cvt fp32->bf16, swizzled write (1 chunk/thread)
    int row = tid >> 4, c16 = tid & 15;
    const float* src;
    if (isW){ int q = qseq[tok0+row]; src = q_emb + (size_t)q*DKD + c16*8; }
    else    { int x = qseq[tok0+row] + NQ*cseq[tok0+row]; src = v_emb + (size_t)x*DKD + c16*8; }
    *(bh8*)(As + swz(row, c16, 256)) = cvt8(src);
  }
  if (isW){ // stage B = Mk (64 rows x 16 chunks), fp32 -> bf16
    #pragma unroll
    for (int m = 0; m < 2; ++m){
      int idx = tid + 512*m; int row = idx >> 4, c16 = idx & 15;
      *(bh8*)(Bs + swz(row, c16, 256)) = cvt8(Mk + (size_t)row*DKD + c16*8);
    }
  } else {  // stage B = [eW; aW] (256 rows x 16 chunks), fp32 -> bf16
    #pragma unroll
    for (int m = 0; m < 8; ++m){
      int idx = tid + 512*m; int row = idx >> 4, c16 = idx & 15;
      const float* src = (row < 128) ? (eW + (size_t)row*DKD) : (aW + (size_t)(row-128)*DKD);
      *(bh8*)(Bs + swz(row, c16, 256)) = cvt8(src + c16*8);
    }
  }
  __syncthreads();

  if (isW){
    const int m = wv & 1, n = wv >> 1;        // 8 waves -> 8 output tiles
    f32x4 acc = {0.f,0.f,0.f,0.f};
    #pragma unroll
    for (int kc = 0; kc < 4; ++kc){
      bh8 af = *(const bh8*)(As + swz(m*16 + (l&15), kc*4 + (l>>4), 256));
      bh8 bf = *(const bh8*)(Bs + swz(n*16 + (l&15), kc*4 + (l>>4), 256));
      acc = __builtin_amdgcn_mfma_f32_16x16x32_bf16(af, bf, acc, 0, 0, 0);
    }
    #pragma unroll
    for (int r = 0; r < 4; ++r){
      int tok = m*16 + (l>>4)*4 + r, out = n*16 + (l&15);
      Ls[tok*68 + out] = acc[r];
    }
    __syncthreads();
    // softmax: wave wv owns tokens 4wv..4wv+3; lane = slot
    #pragma unroll
    for (int i = 0; i < 4; ++i){
      int tok = wv*4 + i;
      float x = Ls[tok*68 + l];
      float mx = x;
      #pragma unroll
      for (int off = 32; off >= 1; off >>= 1) mx = fmaxf(mx, __shfl_xor(mx, off));
      float p = __expf(x - mx);
      float s = p;
      #pragma unroll
      for (int off = 32; off >= 1; off >>= 1) s += __shfl_xor(s, off);
      w_out[(size_t)(tok0+tok)*SLOTS + l] = p / s;
    }
  } else {
    const int m = wv & 1, nq = (wv >> 1) * 4; // 4 n-tiles per wave
    f32x4 acc[4] = {{0.f,0.f,0.f,0.f},{0.f,0.f,0.f,0.f},{0.f,0.f,0.f,0.f},{0.f,0.f,0.f,0.f}};
    #pragma unroll
    for (int kc = 0; kc < 4; ++kc){
      bh8 af = *(const bh8*)(As + swz(m*16 + (l&15), kc*4 + (l>>4), 256));
      #pragma unroll
      for (int j = 0; j < 4; ++j){
        bh8 bf = *(const bh8*)(Bs + swz((nq+j)*16 + (l&15), kc*4 + (l>>4), 256));
        acc[j] = __builtin_amdgcn_mfma_f32_16x16x32_bf16(af, bf, acc[j], 0, 0, 0);
      }
    }
    // transposed store: 4 acc values = 4 consecutive tokens at fixed d -> one float4
    #pragma unroll
    for (int j = 0; j < 4; ++j){
      int out = (nq+j)*16 + (l&15);
      bool is_e = (out < 128);
      int dd = out & 127;
      float bias = is_e ? eb[dd] : ab[dd];
      f32x4 sv;
      #pragma unroll
      for (int r = 0; r < 4; ++r){
        float xv = acc[j][r] + bias;
        sv[r] = is_e ? sigmoidf_(xv) : tanhf_(xv);
      }
      int tg = tok0 + m*16 + (l>>4)*4;       // first of 4 consecutive tokens
      int bb = tg / SEQL, tl = tg - bb*SEQL;
      float* dst = (is_e ? eT : aT) + ((size_t)bb*DKD + dd)*SEQL + tl;
      *(f32x4*)dst = sv;
    }
  }
}

// ---------------- Scan R7: e/a LDS-staged once (no per-chunk barriers); w in pinned
// ---------------- 3-set register rotation from coalesced global; XCD-swizzled blocks.
__device__ __forceinline__ float dpp_row_sum16(float x){
  float t;
  t = __builtin_bit_cast(float, __builtin_amdgcn_update_dpp(0, __builtin_bit_cast(int,x), 0x111, 0xf, 0xf, true)); x += t; // row_shr:1
  t = __builtin_bit_cast(float, __builtin_amdgcn_update_dpp(0, __builtin_bit_cast(int,x), 0x112, 0xf, 0xf, true)); x += t; // row_shr:2
  t = __builtin_bit_cast(float, __builtin_amdgcn_update_dpp(0, __builtin_bit_cast(int,x), 0x114, 0xf, 0xf, true)); x += t; // row_shr:4
  t = __builtin_bit_cast(float, __builtin_amdgcn_update_dpp(0, __builtin_bit_cast(int,x), 0x118, 0xf, 0xf, true)); x += t; // row_shr:8
  return x;  // lane 15 (mod 16) holds the 16-lane sum
}

#define TCH 8   // t per register set; 25 chunks = 200 t

__global__ __launch_bounds__(256) void scan_kernel(
    const float* __restrict__ Mv0,
    const float* __restrict__ w_in,  // [b][200 t][64 s]
    const float* __restrict__ eT,    // [b][128 d][200 t]
    const float* __restrict__ aT,
    u16* __restrict__ r16)           // [b][200 t][128 d]
{
  __shared__ float eS[16][204];      // block's e slice, [c][t], pad 204 (banks 0,12,24,4)
  __shared__ float aS[16][204];
  const int tid = threadIdx.x;
  const int bid = blockIdx.x;
  const int b   = bid & 63;          // all 8 d-blocks of b share XCD (64 % 8 == 0)
  const int d0  = (bid >> 6) << 4;
  const int c   = tid >> 4;          // chain: d = d0 + c
  const int g   = tid & 15;          // slot quad: slots 4g..4g+3
  const int d   = d0 + c;
  const bool wl = (g == 15);

  // ---- stage e/a slices (25.6 KB) with coalesced float4 streaming, ONE barrier ----
  #pragma unroll
  for (int m = 0; m < 7; ++m){
    int i = tid + 256*m;
    if (i < 1600){
      int arr = (i >= 800);
      int j = arr ? i - 800 : i;
      int row = j / 50, col = j - row*50;
      const float* src = (arr ? aT : eT) + ((size_t)b*DKD + d0 + row)*SEQL + col*4;
      float4 v = *(const float4*)src;
      float* dst = (arr ? &aS[0][0] : &eS[0][0]) + row*204 + col*4;
      *(float4*)dst = v;
    }
  }

  float mv0 = Mv0[(4*g+0)*DKD + d];
  float mv1 = Mv0[(4*g+1)*DKD + d];
  float mv2 = Mv0[(4*g+2)*DKD + d];
  float mv3 = Mv0[(4*g+3)*DKD + d];

  const float* wsrc = w_in + (size_t)b*SEQL*SLOTS + 4*g;
  u16* rp = r16 + (size_t)b*SEQL*DKD + d;

  f32x4 Aw[TCH], Bw[TCH], Cw[TCH];

  // full compiler memory barrier after each LOADS: stops IR-level load sinking
  #define LOADS(S, CK) { \
    _Pragma("unroll") \
    for (int i = 0; i < TCH; ++i) \
      S[i] = *(const f32x4*)(wsrc + (size_t)((CK)*TCH + i)*SLOTS); \
    asm volatile("" ::: "memory"); }

  #define CHUNK(S, CK) { \
    _Pragma("unroll") \
    for (int u = 0; u < 2; ++u){ \
      float eq[4], aq[4]; \
      *(float4*)eq = *(const float4*)&eS[c][(CK)*TCH + u*4]; \
      *(float4*)aq = *(const float4*)&aS[c][(CK)*TCH + u*4]; \
      _Pragma("unroll") \
      for (int v = 0; v < 4; ++v){ \
        const int tt = u*4 + v; \
        const float w0 = S[tt][0], w1 = S[tt][1], w2 = S[tt][2], w3 = S[tt][3]; \
        float r = w0*mv0; r = fmaf(w1, mv1, r); \
        r = fmaf(w2, mv2, r); r = fmaf(w3, mv3, r); \
        r = dpp_row_sum16(r); \
        if (wl) rp[(size_t)((CK)*TCH + tt)*DKD] = f2b(r); \
        const float ev = eq[v], av = aq[v]; \
        mv0 = fmaf(w0, fmaf(-mv0, ev, av), mv0); \
        mv1 = fmaf(w1, fmaf(-mv1, ev, av), mv1); \
        mv2 = fmaf(w2, fmaf(-mv2, ev, av), mv2); \
        mv3 = fmaf(w3, fmaf(-mv3, ev, av), mv3); \
      } \
    } }

  LOADS(Aw, 0)
  LOADS(Bw, 1)
  __syncthreads();                   // eS/aS ready (also drains the A/B w-loads, one-time)

  #pragma unroll 1
  for (int m = 0; m < 7; ++m){
    const int ck = 3*m;
    LOADS(Cw, ck+2)  CHUNK(Aw, ck)
    LOADS(Aw, ck+3)  CHUNK(Bw, ck+1)
    LOADS(Bw, ck+4)  CHUNK(Cw, ck+2)
  }
  // tail: chunks 21..24 (A holds 21, B holds 22 after the loop)
  LOADS(Cw, 23)  CHUNK(Aw, 21)
  LOADS(Aw, 24)  CHUNK(Bw, 22)
  CHUNK(Cw, 23)
  CHUNK(Aw, 24)
  #undef LOADS
  #undef CHUNK
}

// ---------------- P3: f = tanh([read|k] fW^T + fb); out = sigmoid(f pW + pb) ----------------
// 512 thr = 8 waves; 32 tok/block; A = [r16 | k] bf16 (K=256), B = fW cvt'd. LDS 80 KiB.
__global__ __launch_bounds__(512) void p3_kernel(
    const int* __restrict__ qseq, const float* __restrict__ q_emb,
    const u16* __restrict__ r16, const float* __restrict__ fW,
    const float* __restrict__ fb, const float* __restrict__ pW,
    const float* __restrict__ pb, float* __restrict__ out)
{
  __shared__ __align__(16) char smem[81920];
  char* As = smem;            // [32 rows][512B]
  char* Bs = smem + 16384;    // [128 rows][512B]

  const int tid = threadIdx.x;
  const int l = tid & 63, wv = tid >> 6;
  const int tok0 = blockIdx.x * 32;

  #pragma unroll
  for (int m = 0; m < 2; ++m){   // stage A: 1024 chunks (rows 512B = 32 chunks)
    int idx = tid + 512*m; int row = idx >> 5, c16 = idx & 31;
    bh8 v;
    if (c16 < 16){
      v = *(const bh8*)(r16 + (size_t)(tok0+row)*DKD + c16*8);
    } else {
      int q = qseq[tok0+row];
      v = cvt8(q_emb + (size_t)q*DKD + (c16-16)*8);
    }
    *(bh8*)(As + swz(row, c16, 512)) = v;
  }
  #pragma unroll
  for (int m = 0; m < 8; ++m){   // stage B: 4096 chunks, fp32 fW -> bf16
    int idx = tid + 512*m; int row = idx >> 5, c16 = idx & 31;
    *(bh8*)(Bs + swz(row, c16, 512)) = cvt8(fW + (size_t)row*256 + c16*8);
  }
  __syncthreads();

  const int m = wv & 1, np = (wv >> 1) * 2;   // 2 n-tiles per wave
  f32x4 acc[2] = {{0.f,0.f,0.f,0.f},{0.f,0.f,0.f,0.f}};
  #pragma unroll
  for (int kc = 0; kc < 8; ++kc){
    bh8 af = *(const bh8*)(As + swz(m*16 + (l&15), kc*4 + (l>>4), 512));
    #pragma unroll
    for (int j = 0; j < 2; ++j){
      bh8 bf = *(const bh8*)(Bs + swz((np+j)*16 + (l&15), kc*4 + (l>>4), 512));
      acc[j] = __builtin_amdgcn_mfma_f32_16x16x32_bf16(af, bf, acc[j], 0, 0, 0);
    }
  }
  // per-lane partial p over this wave's 32 out-columns
  float pp[4] = {0.f,0.f,0.f,0.f};
  #pragma unroll
  for (int j = 0; j < 2; ++j){
    int o = (np+j)*16 + (l&15);
    float bias = fb[o], pw = pW[o];
    #pragma unroll
    for (int r = 0; r < 4; ++r){
      float f = tanhf_(acc[j][r] + bias);
      pp[r] = fmaf(f, pw, pp[r]);
    }
  }
  #pragma unroll
  for (int r = 0; r < 4; ++r){   // reduce across the 16 out-lanes
    pp[r] += __shfl_xor(pp[r], 1);
    pp[r] += __shfl_xor(pp[r], 2);
    pp[r] += __shfl_xor(pp[r], 4);
    pp[r] += __shfl_xor(pp[r], 8);
  }
  __syncthreads();
  float* pbuf = (float*)smem;    // overlay on As (done with it): [8 waves][32 tok]
  if ((l & 15) == 0){
    #pragma unroll
    for (int r = 0; r < 4; ++r){
      int tok = m*16 + (l>>4)*4 + r;
      pbuf[wv*32 + tok] = pp[r];
    }
  }
  __syncthreads();
  if (tid < 32){
    int mm = tid >> 4;   // token's m-half -> waves with wv&1 == mm
    float s = pbuf[(mm+0)*32 + tid] + pbuf[(mm+2)*32 + tid]
            + pbuf[(mm+4)*32 + tid] + pbuf[(mm+6)*32 + tid];
    out[tok0 + tid] = sigmoidf_(s + pb[0]);
  }
}

extern "C" void kernel_launch(void* const* d_in, const int* in_sizes, int n_in,
                              void* d_out, int out_size, void* d_ws, size_t ws_size,
                              hipStream_t stream) {
  const int*   qseq  = (const int*)d_in[0];
  const int*   cseq  = (const int*)d_in[1];
  const float* q_emb = (const float*)d_in[2];
  const float* v_emb = (const float*)d_in[3];
  const float* Mk    = (const float*)d_in[4];
  const float* Mv0   = (const float*)d_in[5];
  const float* eW    = (const float*)d_in[6];
  const float* eb    = (const float*)d_in[7];
  const float* aW    = (const float*)d_in[8];
  const float* ab    = (const float*)d_in[9];
  const float* fW    = (const float*)d_in[10];
  const float* fb    = (const float*)d_in[11];
  const float* pW    = (const float*)d_in[12];
  const float* pb    = (const float*)d_in[13];

  char* ws = (char*)d_ws;
  float* w_buf = (float*)ws;                                   // [b][t][s]  3,276,800
  float* eT    = (float*)(ws + 3276800);                       // [b][d][t]  6,553,600
  float* aT    = (float*)(ws + 9830400);                       // [b][d][t]  6,553,600
  u16*   r16   = (u16*)  (ws + 16384000);                      // [b][t][d]  3,276,800 (end ~19.7 MB)
  float* outp  = (float*)d_out;

  hipLaunchKernelGGL(wea_kernel, dim3(800), dim3(512), 0, stream,
                     qseq, cseq, q_emb, v_emb, Mk, eW, aW, eb, ab,
                     w_buf, eT, aT);
  hipLaunchKernelGGL(scan_kernel, dim3(512), dim3(256), 0, stream,
                     Mv0, w_buf, eT, aT, r16);
  hipLaunchKernelGGL(p3_kernel, dim3(NTOK/32), dim3(512), 0, stream,
                     qseq, q_emb, r16, fW, fb, pW, pb, outp);
}